// Round 3
// baseline (184.742 us; speedup 1.0000x reference)
//
#include <hip/hip_runtime.h>
#include <math.h>

#define NB 2
#define NL 256
#define DM 512
#define NH 8
#define DQ 64

typedef float v2f __attribute__((ext_vector_type(2)));

#if __has_builtin(__builtin_elementwise_fma)
__device__ __forceinline__ v2f fmav(v2f a, v2f b, v2f c) {
    return __builtin_elementwise_fma(a, b, c);
}
#else
__device__ __forceinline__ v2f fmav(v2f a, v2f b, v2f c) {
    v2f r; r.x = fmaf(a.x, b.x, c.x); r.y = fmaf(a.y, b.y, c.y); return r;
}
#endif
__device__ __forceinline__ v2f swapv(v2f a) {
    return __builtin_shufflevector(a, a, 1, 0);
}

// ---------------------------------------------------------------------------
// K1: QKV projection GEMM (R16-passed, unchanged). Register double-buffered.
// z==1 (k): TRANSPOSED (b,h,d,t). z==2 (v): computes u = (v+bias)@Win_h.
// ---------------------------------------------------------------------------
__global__ __launch_bounds__(256) void qkv_gemm(
    const float* __restrict__ xq, const float* __restrict__ xk,
    const float* __restrict__ xv,
    const float* __restrict__ Wq, const float* __restrict__ Wk,
    const float* __restrict__ Wv,
    const float* __restrict__ bq, const float* __restrict__ bk,
    const float* __restrict__ bv,
    const float* __restrict__ Wre, const float* __restrict__ Wim,
    float* __restrict__ q, float* __restrict__ kT, float2* __restrict__ u)
{
    int z = blockIdx.z;
    const float* X = (z == 0) ? xq : (z == 1) ? xk : xv;
    const float* W = (z == 0) ? Wq : (z == 1) ? Wk : Wv;
    const float* bias = (z == 0) ? bq : (z == 1) ? bk : bv;

    __shared__ float As[32][33];
    __shared__ float Bs[32][68];

    int tid = threadIdx.x;
    int tx = tid & 15, ty = tid >> 4;
    int m0 = blockIdx.y * 32, n0 = blockIdx.x * 64;

    int ar = tid >> 3, ac4 = (tid & 7) * 4;
    int br = tid >> 4, bc4 = (tid & 15) * 4;
    const float* Aptr = X + (m0 + ar) * 512 + ac4;
    const float* Bptr0 = W + br * 512 + n0 + bc4;
    const float* Bptr1 = W + (br + 16) * 512 + n0 + bc4;

    float acc[2][4] = {};

    float4 aR = *(const float4*)(Aptr);
    float4 bR0 = *(const float4*)(Bptr0);
    float4 bR1 = *(const float4*)(Bptr1);

    for (int k0 = 0; k0 < 512; k0 += 32) {
        As[ac4 + 0][ar] = aR.x; As[ac4 + 1][ar] = aR.y;
        As[ac4 + 2][ar] = aR.z; As[ac4 + 3][ar] = aR.w;
        *(float4*)&Bs[br][bc4] = bR0;
        *(float4*)&Bs[br + 16][bc4] = bR1;
        __syncthreads();

        if (k0 + 32 < 512) {
            aR  = *(const float4*)(Aptr + k0 + 32);
            bR0 = *(const float4*)(Bptr0 + (k0 + 32) * 512);
            bR1 = *(const float4*)(Bptr1 + (k0 + 32) * 512);
        }

        #pragma unroll
        for (int kk = 0; kk < 32; kk++) {
            float a0 = As[kk][ty * 2 + 0];
            float a1 = As[kk][ty * 2 + 1];
            float4 bb = *(const float4*)&Bs[kk][tx * 4];
            acc[0][0] += a0 * bb.x; acc[0][1] += a0 * bb.y;
            acc[0][2] += a0 * bb.z; acc[0][3] += a0 * bb.w;
            acc[1][0] += a1 * bb.x; acc[1][1] += a1 * bb.y;
            acc[1][2] += a1 * bb.z; acc[1][3] += a1 * bb.w;
        }
        __syncthreads();
    }

    if (z < 2) {
        float* O = (z == 0) ? q : kT;
        #pragma unroll
        for (int i = 0; i < 2; i++) {
            int m = m0 + ty * 2 + i;
            int b = m >> 8, l = m & 255;
            #pragma unroll
            for (int j = 0; j < 4; j++) {
                int n = n0 + tx * 4 + j;
                int h = n >> 6, d = n & 63;
                float val = acc[i][j] + bias[n];
                if (z == 1)
                    O[((b * NH + h) * DQ + d) * NL + l] = val;   // kT
                else
                    O[((b * NH + h) * NL + l) * DQ + d] = val;
            }
        }
    } else {
        int h = blockIdx.x;            // n-tile == head
        int b = m0 >> 8;
        #pragma unroll
        for (int i = 0; i < 2; i++)
            #pragma unroll
            for (int j = 0; j < 4; j++)
                Bs[ty * 2 + i][tx * 4 + j] = acc[i][j] + bias[n0 + tx * 4 + j];
        __syncthreads();

        int r0 = ty * 2, c4 = tx * 4;
        float ur[2][4] = {}, ui[2][4] = {};
        const float* wr = Wre + h * 4096 + c4;
        const float* wi = Wim + h * 4096 + c4;
        #pragma unroll 4
        for (int d = 0; d < 64; d++) {
            float v0 = Bs[r0][d];
            float v1 = Bs[r0 + 1][d];
            float4 wre = *(const float4*)(wr + d * 64);
            float4 wim = *(const float4*)(wi + d * 64);
            ur[0][0] += v0 * wre.x; ur[0][1] += v0 * wre.y;
            ur[0][2] += v0 * wre.z; ur[0][3] += v0 * wre.w;
            ui[0][0] += v0 * wim.x; ui[0][1] += v0 * wim.y;
            ui[0][2] += v0 * wim.z; ui[0][3] += v0 * wim.w;
            ur[1][0] += v1 * wre.x; ur[1][1] += v1 * wre.y;
            ur[1][2] += v1 * wre.z; ur[1][3] += v1 * wre.w;
            ui[1][0] += v1 * wim.x; ui[1][1] += v1 * wim.y;
            ui[1][2] += v1 * wim.z; ui[1][3] += v1 * wim.w;
        }
        #pragma unroll
        for (int i = 0; i < 2; i++) {
            int l = (m0 & 255) + r0 + i;
            float2* up = u + ((size_t)(b * NH + h) * NL + l) * DQ + c4;
            #pragma unroll
            for (int j = 0; j < 4; j++)
                up[j] = make_float2(ur[i][j], ui[i][j]);
        }
    }
}

// ---------------------------------------------------------------------------
// K2: attn softmax prologue + EUNN recurrence.
// THIS ROUND: 2 dims/lane, 2 rows/wave (interleaved: row = lane&1,
// p = lane>>1 owns dims 2p,2p+1 of its row). 4096 rows / 2 = 2048 waves
// = 2 waves/SIMD (R2 had 1) -> second wave fills the 45% stall slots the
// in-order wave exposed at 1/SIMD.
//   - stage-0 pair (2p,2p+1) fully intra-lane (0 cross-lane ops)
//   - stage-1 exchange: even dim needs lane-2's g_b, odd dim needs lane+2's
//     g_a -> wave rotate by +/-2 (2x chained wf rotate DPP, parity-preserving
//     so rows never mix; p wraps mod 32 naturally via the mod-64 lane wrap)
//   - per-dim fma chains / coefficients / modrelu verbatim from the
//     R2-passed kernel -> bitwise-identical numerics
//   - u loads: one float4 per lane per step (u shared by both rows);
//     double-buffered in 4-step chunks as in R2
// ---------------------------------------------------------------------------
__device__ __forceinline__ float rot_up2(float x) {   // lane i <- lane (i+2)%64
    int v = __builtin_amdgcn_mov_dpp(__float_as_int(x), 0x134, 0xF, 0xF, true);
    v = __builtin_amdgcn_mov_dpp(v, 0x134, 0xF, 0xF, true);
    return __int_as_float(v);
}
__device__ __forceinline__ float rot_dn2(float x) {   // lane i <- lane (i-2)%64
    int v = __builtin_amdgcn_mov_dpp(__float_as_int(x), 0x13C, 0xF, 0xF, true);
    v = __builtin_amdgcn_mov_dpp(v, 0x13C, 0xF, 0xF, true);
    return __int_as_float(v);
}

__device__ __forceinline__ v2f mdr(v2f z, float bv) {      // modrelu, exact reference form
    float mm = z.x * z.x + z.y * z.y;
    float m = __builtin_amdgcn_sqrtf(mm);
    float sc = fmaxf(m + bv, 0.f) * __builtin_amdgcn_rcpf(m + 1e-5f);
    v2f s = {sc, sc};
    return z * s;
}

__global__ __launch_bounds__(64) void rnn_kernel(
    const float* __restrict__ q, const float* __restrict__ kT,
    const float* __restrict__ mask, float* __restrict__ attn_o,
    const float2* __restrict__ u,
    const float* __restrict__ theta, const float* __restrict__ phi,
    const float* __restrict__ rnn_bias, float* __restrict__ rnn_out)
{
    int lane = threadIdx.x;       // block = 1 wave
    int blk = blockIdx.x;         // 2048 blocks: b(1) | h(3) | qg(7)
    int qg = blk & 127;           // pair of q rows: 2qg, 2qg+1
    int h  = (blk >> 7) & 7;
    int b  = blk >> 10;

    int row = lane & 1;           // q-row within pair
    int p   = lane >> 1;          // 0..31; owns dims 2p, 2p+1

    __shared__ float qs[2][68];       // +4 float row skew
    __shared__ float arow[2][260];

    // ---------------- load q rows (2 x 64) ----------------
    {
        const float4* qsrc = (const float4*)(q + ((size_t)(b * NH + h) * NL + qg * 2) * DQ);
        if (lane < 32) {
            float4 f4 = qsrc[lane];
            *(float4*)&qs[lane >> 4][(lane & 15) * 4] = f4;
        }
    }
    __syncthreads();

    // ---------------- QK^T + softmax (keys: lane + 64*kk) ----------------
    {
        const float* kp = kT + (size_t)((b * NH + h) * DQ) * NL + lane;
        float acc[2][4] = {};
        #pragma unroll
        for (int d4 = 0; d4 < 16; d4++) {
            float kv[4][4];
            #pragma unroll
            for (int kk = 0; kk < 4; kk++)
                #pragma unroll
                for (int i = 0; i < 4; i++)
                    kv[kk][i] = kp[(size_t)(d4 * 4 + i) * NL + kk * 64];
            #pragma unroll
            for (int r = 0; r < 2; r++) {
                float4 qv = *(const float4*)&qs[r][d4 * 4];
                #pragma unroll
                for (int kk = 0; kk < 4; kk++)
                    acc[r][kk] += qv.x * kv[kk][0] + qv.y * kv[kk][1]
                                + qv.z * kv[kk][2] + qv.w * kv[kk][3];
            }
        }
        float l[2][4];
        #pragma unroll
        for (int r = 0; r < 2; r++)
            #pragma unroll
            for (int kk = 0; kk < 4; kk++) {
                float mv = mask[(size_t)(b * NL + qg * 2 + r) * NL + lane + kk * 64];
                l[r][kk] = acc[r][kk] * 0.125f - ((mv == 1.0f) ? INFINITY : mv);
            }
        #pragma unroll
        for (int r = 0; r < 2; r++) {
            float mx = fmaxf(fmaxf(l[r][0], l[r][1]), fmaxf(l[r][2], l[r][3]));
            #pragma unroll
            for (int o = 32; o; o >>= 1) mx = fmaxf(mx, __shfl_xor(mx, o, 64));
            float s = __expf(l[r][0] - mx) + __expf(l[r][1] - mx)
                    + __expf(l[r][2] - mx) + __expf(l[r][3] - mx);
            #pragma unroll
            for (int o = 32; o; o >>= 1) s += __shfl_xor(s, o, 64);
            float rs = __builtin_amdgcn_rcpf(s);
            #pragma unroll
            for (int kk = 0; kk < 4; kk++) {
                float pv = __expf(l[r][kk] - mx) * rs;
                attn_o[((size_t)(b * NH + h) * NL + qg * 2 + r) * NL + lane + kk * 64] = pv;
                arow[r][lane + kk * 64] = pv;
            }
        }
    }
    __syncthreads();

    // ---------------- EUNN recurrence (2 dims/lane) ----------------
    const float* tb = theta + h * 64;     // (8,2,32): c=0 at [0..31], c=1 at [32..63]
    const float* pb = phi + h * 64;

    // W coeff helper: given (Wr, Wi): WrV = {Wr,Wr}, WiN = {-Wi, Wi}
    #define MKC(nm, Wr, Wi) v2f nm##rV = {(Wr), (Wr)}; v2f nm##iN = {-(Wi), (Wi)}

    // stage-0 pair p: dims 2p ("a", even), 2p+1 ("b", odd)
    float th0 = tb[p], ph0 = pb[p];
    float c0 = cosf(th0), s0 = sinf(th0), cp0 = cosf(ph0), sp0 = sinf(ph0);
    MKC(WSa, -s0 * cp0, -s0 * sp0);   // even member
    MKC(WSb,  s0 * cp0, -s0 * sp0);   // odd member
    v2f c0v = {c0, c0};

    // stage-1: even dim 2p is "b" member of pair (p+31)&31; partner = lane-2's g_b
    int iE = (p + 31) & 31;
    float thE = tb[32 + iE], phE = pb[32 + iE];
    float cE = cosf(thE), sE = sinf(thE);
    MKC(W1E,  sE * cosf(phE), -sE * sinf(phE));   // even "b" form
    v2f cEv = {cE, cE};
    //           odd dim 2p+1 is "a" member of pair p; partner = lane+2's g_a
    float thO = tb[32 + p], phO = pb[32 + p];
    float cO = cosf(thO), sO = sinf(thO);
    MKC(W1O, -sO * cosf(phO), -sO * sinf(phO));   // odd "a" form
    v2f cOv = {cO, cO};
    #undef MKC

    float2 bias2 = *(const float2*)&rnn_bias[h * 64 + 2 * p];

    v2f ea = {0.f, 0.f}, eb = {0.f, 0.f};

    #define STEP(a_t, uu) do {                                               \
        v2f atv = {(a_t), (a_t)};                                            \
        v2f u0 = {(uu).x, (uu).y}, u1 = {(uu).z, (uu).w};                    \
        v2f ga = fmav(c0v, ea, fmav(WSarV, eb, WSaiN * swapv(eb)));          \
        v2f gb = fmav(c0v, eb, fmav(WSbrV, ea, WSbiN * swapv(ea)));          \
        v2f gl, gr;                                                          \
        gl.x = rot_dn2(gb.x); gl.y = rot_dn2(gb.y);                          \
        gr.x = rot_up2(ga.x); gr.y = rot_up2(ga.y);                          \
        v2f za = fmav(cEv, ga, fmav(W1ErV, gl, fmav(W1EiN, swapv(gl), atv * u0))); \
        v2f zb = fmav(cOv, gb, fmav(W1OrV, gr, fmav(W1OiN, swapv(gr), atv * u1))); \
        ea = mdr(za, bias2.x); eb = mdr(zb, bias2.y);                        \
    } while (0)

    // u stream: lane reads dims 2p,2p+1 at each t -> one float4 per t.
    // (u is shared by both rows; lane pairs load the same address.)
    const float4* up4 = (const float4*)(u + (size_t)((b * NH + h) * NL) * DQ) + p;

    // double-buffered chunks of 4 timesteps: 4 x dwordx4 + 1 x b128 per chunk
    float4 Ua[4], Ub[4];
    float4 aa, ab;
    #pragma unroll
    for (int i = 0; i < 4; i++) Ua[i] = up4[i * 32];
    aa = *(const float4*)&arow[row][0];

    for (int c = 0; c < 64; c += 2) {
        // prefetch chunk c+1 (always exists)
        const float4* upn = up4 + (c + 1) * 128;
        #pragma unroll
        for (int i = 0; i < 4; i++) Ub[i] = upn[i * 32];
        ab = *(const float4*)&arow[row][(c + 1) * 4];

        STEP(aa.x, Ua[0]);
        STEP(aa.y, Ua[1]);
        STEP(aa.z, Ua[2]);
        STEP(aa.w, Ua[3]);

        // prefetch chunk c+2 (guarded; stale regs unused on last trip)
        if (c + 2 < 64) {
            const float4* upn2 = up4 + (c + 2) * 128;
            #pragma unroll
            for (int i = 0; i < 4; i++) Ua[i] = upn2[i * 32];
            aa = *(const float4*)&arow[row][(c + 2) * 4];
        }

        STEP(ab.x, Ub[0]);
        STEP(ab.y, Ub[1]);
        STEP(ab.z, Ub[2]);
        STEP(ab.w, Ub[3]);
    }
    #undef STEP

    int qi = qg * 2 + row;
    *(float2*)&rnn_out[(size_t)(b * NL + qi) * DM + h * DQ + 2 * p] =
        make_float2(ea.x, eb.x);
}

// ---------------------------------------------------------------------------
// K3: output projection (R16-passed, unchanged). Register double-buffered.
// ---------------------------------------------------------------------------
__global__ __launch_bounds__(256) void out_gemm(
    const float* __restrict__ A, const float* __restrict__ W,
    const float* __restrict__ bias, float* __restrict__ C)
{
    __shared__ float As[32][17];
    __shared__ float Bs[32][68];

    int tid = threadIdx.x;
    int tx = tid & 15, ty = tid >> 4;
    int m0 = blockIdx.y * 16, n0 = blockIdx.x * 64;

    int ar = tid >> 4, ac2 = (tid & 15) * 2;
    int br = tid >> 4, bc4 = (tid & 15) * 4;
    const float* Aptr = A + (m0 + ar) * 512 + ac2;
    const float* Bptr0 = W + br * 512 + n0 + bc4;
    const float* Bptr1 = W + (br + 16) * 512 + n0 + bc4;

    float acc[4] = {};

    float2 aR = *(const float2*)(Aptr);
    float4 bR0 = *(const float4*)(Bptr0);
    float4 bR1 = *(const float4*)(Bptr1);

    for (int k0 = 0; k0 < 512; k0 += 32) {
        As[ac2 + 0][ar] = aR.x; As[ac2 + 1][ar] = aR.y;
        *(float4*)&Bs[br][bc4] = bR0;
        *(float4*)&Bs[br + 16][bc4] = bR1;
        __syncthreads();

        if (k0 + 32 < 512) {
            aR  = *(const float2*)(Aptr + k0 + 32);
            bR0 = *(const float4*)(Bptr0 + (k0 + 32) * 512);
            bR1 = *(const float4*)(Bptr1 + (k0 + 32) * 512);
        }

        #pragma unroll
        for (int kk = 0; kk < 32; kk++) {
            float a = As[kk][ty];
            float4 bb = *(const float4*)&Bs[kk][tx * 4];
            acc[0] += a * bb.x; acc[1] += a * bb.y;
            acc[2] += a * bb.z; acc[3] += a * bb.w;
        }
        __syncthreads();
    }

    int m = m0 + ty;
    #pragma unroll
    for (int j = 0; j < 4; j++) {
        int n = n0 + tx * 4 + j;
        C[m * 512 + n] = acc[j] + bias[n];
    }
}

// ---------------------------------------------------------------------------
extern "C" void kernel_launch(void* const* d_in, const int* in_sizes, int n_in,
                              void* d_out, int out_size, void* d_ws, size_t ws_size,
                              hipStream_t stream)
{
    const float* x_q  = (const float*)d_in[0];
    const float* x_k  = (const float*)d_in[1];
    const float* x_v  = (const float*)d_in[2];
    const float* mask = (const float*)d_in[3];
    const float* Wq   = (const float*)d_in[4];
    const float* bq   = (const float*)d_in[5];
    const float* Wk   = (const float*)d_in[6];
    const float* bk   = (const float*)d_in[7];
    const float* Wv   = (const float*)d_in[8];
    const float* bv   = (const float*)d_in[9];
    const float* Wo   = (const float*)d_in[10];
    const float* bo   = (const float*)d_in[11];
    const float* theta= (const float*)d_in[12];
    const float* phi  = (const float*)d_in[13];
    const float* Wre  = (const float*)d_in[14];
    const float* Wim  = (const float*)d_in[15];
    const float* rb   = (const float*)d_in[16];

    float* ws = (float*)d_ws;
    float*  q_ws    = ws;                       // 262144 f
    float*  kT_ws   = ws + 262144;              // 262144 f (b,h,d,t)
    float2* u_ws    = (float2*)(ws + 524288);   // 262144 float2
    float*  rnn_o   = ws + 1048576;             // 262144 f

    float* out_o  = (float*)d_out;              // (2,256,512)
    float* attn_o = out_o + NB * NL * DM;       // (2,8,256,256)

    qkv_gemm<<<dim3(8, 16, 3), 256, 0, stream>>>(
        x_q, x_k, x_v, Wq, Wk, Wv, bq, bk, bv, Wre, Wim,
        q_ws, kT_ws, u_ws);

    rnn_kernel<<<dim3(2048), 64, 0, stream>>>(
        q_ws, kT_ws, mask, attn_o, u_ws, theta, phi, rb, rnn_o);

    out_gemm<<<dim3(8, 32), 256, 0, stream>>>(rnn_o, Wo, bo, out_o);
}